// Round 9
// baseline (150.634 us; speedup 1.0000x reference)
//
#include <hip/hip_runtime.h>
#include <hip/hip_bf16.h>

#define DI 4096
#define DM 2048
#define NS 128
#define BB 128

typedef __attribute__((ext_vector_type(8))) short bf16x8;
typedef __attribute__((ext_vector_type(4))) float f32x4;

__device__ __forceinline__ unsigned short f2bf(float f) {
  union { __hip_bfloat16 h; unsigned short u; } c;
  c.h = __float2bfloat16(f);
  return c.u;
}

// C[b][n] = sum_k X[b][k] * W[n][k], K split NSPLIT ways into partials.
// Block tile: M=128 x N=32, K-step 32. 4 waves as 2(M) x 2(N).
// 2-deep ping-pong prefetch (R7-proven).
template<int N, int K, int NSPLIT>
__global__ __launch_bounds__(256) void gemm_bf16(
    const float* __restrict__ Xg, const float* __restrict__ Wg,
    float* __restrict__ part) {
  constexpr int NBLKS = N / 32;
  constexpr int KS = K / NSPLIT;
  constexpr int NSTEPS = KS / 32;
  static_assert(NSTEPS % 2 == 0, "2-unrolled pipeline needs even NSTEPS");
  const int nblk = blockIdx.x % NBLKS;
  const int ks   = blockIdx.x / NBLKS;
  const int kbase = ks * KS;
  const int tid = threadIdx.x;
  const int lane = tid & 63;
  const int wid = tid >> 6;
  const int wr = wid & 1;
  const int wc = wid >> 1;
  const int r16 = lane & 15;
  const int kb = lane >> 4;

  __shared__ __hip_bfloat16 As[128][40];
  __shared__ __hip_bfloat16 Bs[32][40];

  const int arow = tid >> 3;
  const int seg  = tid & 7;

  f32x4 acc[4] = { {0,0,0,0}, {0,0,0,0}, {0,0,0,0}, {0,0,0,0} };

  const float* aG = Xg + (size_t)arow * K + kbase + seg * 4;
  const float* bG = Wg + (size_t)(nblk * 32 + arow) * K + kbase + seg * 4;

  float4 qa0, qa1, qa2, qa3, qb;   // set A
  float4 ra0, ra1, ra2, ra3, rb;   // set B
  qa0 = *(const float4*)(aG + 0 * 32 * K);
  qa1 = *(const float4*)(aG + 1 * 32 * K);
  qa2 = *(const float4*)(aG + 2 * 32 * K);
  qa3 = *(const float4*)(aG + 3 * 32 * K);
  qb  = *(const float4*)(bG);
  ra0 = *(const float4*)(aG + 32 + 0 * 32 * K);
  ra1 = *(const float4*)(aG + 32 + 1 * 32 * K);
  ra2 = *(const float4*)(aG + 32 + 2 * 32 * K);
  ra3 = *(const float4*)(aG + 32 + 3 * 32 * K);
  rb  = *(const float4*)(bG + 32);

  for (int s = 0; s < NSTEPS; s += 2) {
    if (s) __syncthreads();
    {
      ushort4 h;
      h.x = f2bf(qa0.x); h.y = f2bf(qa0.y); h.z = f2bf(qa0.z); h.w = f2bf(qa0.w);
      *(ushort4*)&As[arow +  0][seg * 4] = h;
      h.x = f2bf(qa1.x); h.y = f2bf(qa1.y); h.z = f2bf(qa1.z); h.w = f2bf(qa1.w);
      *(ushort4*)&As[arow + 32][seg * 4] = h;
      h.x = f2bf(qa2.x); h.y = f2bf(qa2.y); h.z = f2bf(qa2.z); h.w = f2bf(qa2.w);
      *(ushort4*)&As[arow + 64][seg * 4] = h;
      h.x = f2bf(qa3.x); h.y = f2bf(qa3.y); h.z = f2bf(qa3.z); h.w = f2bf(qa3.w);
      *(ushort4*)&As[arow + 96][seg * 4] = h;
      h.x = f2bf(qb.x);  h.y = f2bf(qb.y);  h.z = f2bf(qb.z);  h.w = f2bf(qb.w);
      *(ushort4*)&Bs[arow][seg * 4] = h;
    }
    if (s + 2 < NSTEPS) {
      const int o = (s + 2) * 32;
      qa0 = *(const float4*)(aG + o + 0 * 32 * K);
      qa1 = *(const float4*)(aG + o + 1 * 32 * K);
      qa2 = *(const float4*)(aG + o + 2 * 32 * K);
      qa3 = *(const float4*)(aG + o + 3 * 32 * K);
      qb  = *(const float4*)(bG + o);
    }
    __syncthreads();
    {
      bf16x8 bv = *(const bf16x8*)&Bs[wc * 16 + r16][kb * 8];
#pragma unroll
      for (int m = 0; m < 4; ++m) {
        bf16x8 av = *(const bf16x8*)&As[wr * 64 + m * 16 + r16][kb * 8];
        acc[m] = __builtin_amdgcn_mfma_f32_16x16x32_bf16(av, bv, acc[m], 0, 0, 0);
      }
    }
    __syncthreads();
    {
      ushort4 h;
      h.x = f2bf(ra0.x); h.y = f2bf(ra0.y); h.z = f2bf(ra0.z); h.w = f2bf(ra0.w);
      *(ushort4*)&As[arow +  0][seg * 4] = h;
      h.x = f2bf(ra1.x); h.y = f2bf(ra1.y); h.z = f2bf(ra1.z); h.w = f2bf(ra1.w);
      *(ushort4*)&As[arow + 32][seg * 4] = h;
      h.x = f2bf(ra2.x); h.y = f2bf(ra2.y); h.z = f2bf(ra2.z); h.w = f2bf(ra2.w);
      *(ushort4*)&As[arow + 64][seg * 4] = h;
      h.x = f2bf(ra3.x); h.y = f2bf(ra3.y); h.z = f2bf(ra3.z); h.w = f2bf(ra3.w);
      *(ushort4*)&As[arow + 96][seg * 4] = h;
      h.x = f2bf(rb.x);  h.y = f2bf(rb.y);  h.z = f2bf(rb.z);  h.w = f2bf(rb.w);
      *(ushort4*)&Bs[arow][seg * 4] = h;
    }
    if (s + 3 < NSTEPS) {
      const int o = (s + 3) * 32;
      ra0 = *(const float4*)(aG + o + 0 * 32 * K);
      ra1 = *(const float4*)(aG + o + 1 * 32 * K);
      ra2 = *(const float4*)(aG + o + 2 * 32 * K);
      ra3 = *(const float4*)(aG + o + 3 * 32 * K);
      rb  = *(const float4*)(bG + o);
    }
    __syncthreads();
    {
      bf16x8 bv = *(const bf16x8*)&Bs[wc * 16 + r16][kb * 8];
#pragma unroll
      for (int m = 0; m < 4; ++m) {
        bf16x8 av = *(const bf16x8*)&As[wr * 64 + m * 16 + r16][kb * 8];
        acc[m] = __builtin_amdgcn_mfma_f32_16x16x32_bf16(av, bv, acc[m], 0, 0, 0);
      }
    }
  }

  // C/D layout: col = lane&15, row = (lane>>4)*4 + reg   [guide §3, verified]
  const int ncol = nblk * 32 + wc * 16 + r16;
#pragma unroll
  for (int m = 0; m < 4; ++m) {
#pragma unroll
    for (int r = 0; r < 4; ++r) {
      int brow = wr * 64 + m * 16 + kb * 4 + r;
      part[(size_t)(ks * 128 + brow) * N + ncol] = acc[m][r];
    }
  }
}

// Sum GEMM1 partials + bias, then conv + silu. Emits u and new_conv_state.
// (R1/R7 exact)
__global__ __launch_bounds__(256) void combine1(
    const float* __restrict__ part, const float* __restrict__ b_in,
    const float* __restrict__ conv_state, const float* __restrict__ conv_weight,
    float* __restrict__ u_ws, float* __restrict__ ncs) {
  int idx = blockIdx.x * 256 + threadIdx.x;   // b*DI + d, < 524288
  int d = idx & (DI - 1);
  float xp = b_in[d];
#pragma unroll
  for (int s = 0; s < 4; ++s) xp += part[(size_t)s * (BB * DI) + idx];
  const float* cs = conv_state + (size_t)idx * 3;
  float4 w4 = *(const float4*)(conv_weight + d * 4);
  float c0 = cs[0], c1 = cs[1], c2 = cs[2];
  float sv = c0 * w4.x + c1 * w4.y + c2 * w4.z + xp * w4.w;
  float uu = sv / (1.f + __expf(-sv));
  u_ws[idx] = uu;
  float* o = ncs + (size_t)idx * 3;
  o[0] = c1; o[1] = c2; o[2] = xp;
}

// Streaming SSM (R1/R7 body, unroll 8): new_ssm = exp(A)*ssm + B*u ;
// y_in = sum_n C*new_ssm + D*u. unroll 8 doubles in-flight HBM reads
// (4KB -> 8KB per wave) to cover the load->FMA->store chain latency.
__global__ __launch_bounds__(256) void ssm_kernel(
    const float* __restrict__ ssm, const float* __restrict__ A,
    const float* __restrict__ Bp, const float* __restrict__ Cp,
    const float* __restrict__ Dp, const float* __restrict__ u,
    float* __restrict__ nss, float* __restrict__ y_in) {
  const int chunk = blockIdx.x >> 7;   // 0..3 (d-chunk of 1024)
  const int b = blockIdx.x & 127;
  const int d0 = chunk * 1024 + threadIdx.x * 4;
  f32x4 u4  = *(const f32x4*)(u + (size_t)b * DI + d0);
  f32x4 dp4 = *(const f32x4*)(Dp + d0);
  float accx = dp4[0]*u4[0], accy = dp4[1]*u4[1];
  float accz = dp4[2]*u4[2], accw = dp4[3]*u4[3];
  const float* sp = ssm + (size_t)b * NS * DI + d0;
  float* op = nss + (size_t)b * NS * DI + d0;
#pragma unroll 8
  for (int n = 0; n < NS; ++n) {
    f32x4 a4 = *(const f32x4*)(A + (size_t)n * DI + d0);            // L2-resident
    f32x4 s4 = __builtin_nontemporal_load((const f32x4*)(sp + (size_t)n * DI));
    float bn = Bp[n], cn = Cp[n];
    f32x4 ns4;
    ns4[0] = __expf(a4[0]) * s4[0] + bn * u4[0];
    ns4[1] = __expf(a4[1]) * s4[1] + bn * u4[1];
    ns4[2] = __expf(a4[2]) * s4[2] + bn * u4[2];
    ns4[3] = __expf(a4[3]) * s4[3] + bn * u4[3];
    __builtin_nontemporal_store(ns4, (f32x4*)(op + (size_t)n * DI));
    accx += cn * ns4[0]; accy += cn * ns4[1];
    accz += cn * ns4[2]; accw += cn * ns4[3];
  }
  f32x4 r; r[0] = accx; r[1] = accy; r[2] = accz; r[3] = accw;
  *(f32x4*)(y_in + (size_t)b * DI + d0) = r;
}

__global__ __launch_bounds__(256) void combine2(
    const float* __restrict__ part, const float* __restrict__ b_out,
    float* __restrict__ y_t) {
  int idx = blockIdx.x * 256 + threadIdx.x;  // b*DM + j, < 262144
  int j = idx & (DM - 1);
  float v = b_out[j];
#pragma unroll
  for (int s = 0; s < 8; ++s) v += part[(size_t)s * (BB * DM) + idx];
  y_t[idx] = v;
}

extern "C" void kernel_launch(void* const* d_in, const int* in_sizes, int n_in,
                              void* d_out, int out_size, void* d_ws, size_t ws_size,
                              hipStream_t stream) {
  const float* x_t         = (const float*)d_in[0];
  const float* conv_state  = (const float*)d_in[1];
  const float* ssm_state   = (const float*)d_in[2];
  const float* W_in        = (const float*)d_in[3];
  const float* b_in        = (const float*)d_in[4];
  const float* conv_weight = (const float*)d_in[5];
  const float* A           = (const float*)d_in[6];
  const float* Bp          = (const float*)d_in[7];
  const float* Cp          = (const float*)d_in[8];
  const float* Dp          = (const float*)d_in[9];
  const float* W_out       = (const float*)d_in[10];
  const float* b_out       = (const float*)d_in[11];

  float* y_t = (float*)d_out;                       // [128][2048]
  float* ncs = y_t + (size_t)BB * DM;               // [128][4096][3]
  float* nss = ncs + (size_t)BB * DI * 3;           // [128][128][4096]

  float* ws = (float*)d_ws;
  const size_t P1 = 4u * BB * DI;   // 2,097,152 floats
  const size_t P2 = 8u * BB * DM;   // 2,097,152 floats
  const size_t UV = (size_t)BB * DI;
  float *part1, *part2, *u_ws, *y_in;
  if (ws_size >= (P1 + P2 + 2 * UV) * sizeof(float)) {
    part1 = ws; part2 = part1 + P1; u_ws = part2 + P2; y_in = u_ws + UV;
  } else {
    // GEMM1 partials are fully consumed before ssm_kernel writes nss region
    part1 = nss;
    part2 = ws; u_ws = part2 + P2; y_in = u_ws + UV;
  }

  gemm_bf16<DI, DM, 4><<<dim3(512), dim3(256), 0, stream>>>(x_t, W_in, part1);
  combine1<<<dim3(2048), dim3(256), 0, stream>>>(part1, b_in, conv_state,
                                                 conv_weight, u_ws, ncs);
  ssm_kernel<<<dim3(512), dim3(256), 0, stream>>>(ssm_state, A, Bp, Cp, Dp,
                                                  u_ws, nss, y_in);
  gemm_bf16<DM, DI, 8><<<dim3(512), dim3(256), 0, stream>>>(y_in, W_out, part2);
  combine2<<<dim3(1024), dim3(256), 0, stream>>>(part2, b_out, y_t);
}

// Round 11
// 130.098 us; speedup vs baseline: 1.1579x; 1.1579x over previous
//
#include <hip/hip_runtime.h>
#include <hip/hip_bf16.h>

#define DI 4096
#define DM 2048
#define NS 128
#define BB 128

typedef __attribute__((ext_vector_type(8))) short bf16x8;
typedef __attribute__((ext_vector_type(4))) float f32x4;

__device__ __forceinline__ unsigned short f2bf(float f) {
  union { __hip_bfloat16 h; unsigned short u; } c;
  c.h = __float2bfloat16(f);
  return c.u;
}

// C[b][n] = sum_k X[b][k] * W[n][k], K split NSPLIT ways into partials.
// Block tile: M=128 x N=32, K-step 32. 4 waves as 2(M) x 2(N).
// 2-deep ping-pong prefetch (R7-proven best).
template<int N, int K, int NSPLIT>
__global__ __launch_bounds__(256) void gemm_bf16(
    const float* __restrict__ Xg, const float* __restrict__ Wg,
    float* __restrict__ part) {
  constexpr int NBLKS = N / 32;
  constexpr int KS = K / NSPLIT;
  constexpr int NSTEPS = KS / 32;
  static_assert(NSTEPS % 2 == 0, "2-unrolled pipeline needs even NSTEPS");
  const int nblk = blockIdx.x % NBLKS;
  const int ks   = blockIdx.x / NBLKS;
  const int kbase = ks * KS;
  const int tid = threadIdx.x;
  const int lane = tid & 63;
  const int wid = tid >> 6;
  const int wr = wid & 1;
  const int wc = wid >> 1;
  const int r16 = lane & 15;
  const int kb = lane >> 4;

  __shared__ __hip_bfloat16 As[128][40];
  __shared__ __hip_bfloat16 Bs[32][40];

  const int arow = tid >> 3;
  const int seg  = tid & 7;

  f32x4 acc[4] = { {0,0,0,0}, {0,0,0,0}, {0,0,0,0}, {0,0,0,0} };

  const float* aG = Xg + (size_t)arow * K + kbase + seg * 4;
  const float* bG = Wg + (size_t)(nblk * 32 + arow) * K + kbase + seg * 4;

  float4 qa0, qa1, qa2, qa3, qb;   // set A
  float4 ra0, ra1, ra2, ra3, rb;   // set B
  qa0 = *(const float4*)(aG + 0 * 32 * K);
  qa1 = *(const float4*)(aG + 1 * 32 * K);
  qa2 = *(const float4*)(aG + 2 * 32 * K);
  qa3 = *(const float4*)(aG + 3 * 32 * K);
  qb  = *(const float4*)(bG);
  ra0 = *(const float4*)(aG + 32 + 0 * 32 * K);
  ra1 = *(const float4*)(aG + 32 + 1 * 32 * K);
  ra2 = *(const float4*)(aG + 32 + 2 * 32 * K);
  ra3 = *(const float4*)(aG + 32 + 3 * 32 * K);
  rb  = *(const float4*)(bG + 32);

  for (int s = 0; s < NSTEPS; s += 2) {
    if (s) __syncthreads();
    {
      ushort4 h;
      h.x = f2bf(qa0.x); h.y = f2bf(qa0.y); h.z = f2bf(qa0.z); h.w = f2bf(qa0.w);
      *(ushort4*)&As[arow +  0][seg * 4] = h;
      h.x = f2bf(qa1.x); h.y = f2bf(qa1.y); h.z = f2bf(qa1.z); h.w = f2bf(qa1.w);
      *(ushort4*)&As[arow + 32][seg * 4] = h;
      h.x = f2bf(qa2.x); h.y = f2bf(qa2.y); h.z = f2bf(qa2.z); h.w = f2bf(qa2.w);
      *(ushort4*)&As[arow + 64][seg * 4] = h;
      h.x = f2bf(qa3.x); h.y = f2bf(qa3.y); h.z = f2bf(qa3.z); h.w = f2bf(qa3.w);
      *(ushort4*)&As[arow + 96][seg * 4] = h;
      h.x = f2bf(qb.x);  h.y = f2bf(qb.y);  h.z = f2bf(qb.z);  h.w = f2bf(qb.w);
      *(ushort4*)&Bs[arow][seg * 4] = h;
    }
    if (s + 2 < NSTEPS) {
      const int o = (s + 2) * 32;
      qa0 = *(const float4*)(aG + o + 0 * 32 * K);
      qa1 = *(const float4*)(aG + o + 1 * 32 * K);
      qa2 = *(const float4*)(aG + o + 2 * 32 * K);
      qa3 = *(const float4*)(aG + o + 3 * 32 * K);
      qb  = *(const float4*)(bG + o);
    }
    __syncthreads();
    {
      bf16x8 bv = *(const bf16x8*)&Bs[wc * 16 + r16][kb * 8];
#pragma unroll
      for (int m = 0; m < 4; ++m) {
        bf16x8 av = *(const bf16x8*)&As[wr * 64 + m * 16 + r16][kb * 8];
        acc[m] = __builtin_amdgcn_mfma_f32_16x16x32_bf16(av, bv, acc[m], 0, 0, 0);
      }
    }
    __syncthreads();
    {
      ushort4 h;
      h.x = f2bf(ra0.x); h.y = f2bf(ra0.y); h.z = f2bf(ra0.z); h.w = f2bf(ra0.w);
      *(ushort4*)&As[arow +  0][seg * 4] = h;
      h.x = f2bf(ra1.x); h.y = f2bf(ra1.y); h.z = f2bf(ra1.z); h.w = f2bf(ra1.w);
      *(ushort4*)&As[arow + 32][seg * 4] = h;
      h.x = f2bf(ra2.x); h.y = f2bf(ra2.y); h.z = f2bf(ra2.z); h.w = f2bf(ra2.w);
      *(ushort4*)&As[arow + 64][seg * 4] = h;
      h.x = f2bf(ra3.x); h.y = f2bf(ra3.y); h.z = f2bf(ra3.z); h.w = f2bf(ra3.w);
      *(ushort4*)&As[arow + 96][seg * 4] = h;
      h.x = f2bf(rb.x);  h.y = f2bf(rb.y);  h.z = f2bf(rb.z);  h.w = f2bf(rb.w);
      *(ushort4*)&Bs[arow][seg * 4] = h;
    }
    if (s + 3 < NSTEPS) {
      const int o = (s + 3) * 32;
      ra0 = *(const float4*)(aG + o + 0 * 32 * K);
      ra1 = *(const float4*)(aG + o + 1 * 32 * K);
      ra2 = *(const float4*)(aG + o + 2 * 32 * K);
      ra3 = *(const float4*)(aG + o + 3 * 32 * K);
      rb  = *(const float4*)(bG + o);
    }
    __syncthreads();
    {
      bf16x8 bv = *(const bf16x8*)&Bs[wc * 16 + r16][kb * 8];
#pragma unroll
      for (int m = 0; m < 4; ++m) {
        bf16x8 av = *(const bf16x8*)&As[wr * 64 + m * 16 + r16][kb * 8];
        acc[m] = __builtin_amdgcn_mfma_f32_16x16x32_bf16(av, bv, acc[m], 0, 0, 0);
      }
    }
  }

  // C/D layout: col = lane&15, row = (lane>>4)*4 + reg   [guide §3, verified]
  const int ncol = nblk * 32 + wc * 16 + r16;
#pragma unroll
  for (int m = 0; m < 4; ++m) {
#pragma unroll
    for (int r = 0; r < 4; ++r) {
      int brow = wr * 64 + m * 16 + kb * 4 + r;
      part[(size_t)(ks * 128 + brow) * N + ncol] = acc[m][r];
    }
  }
}

// Sum GEMM1 partials + bias, then conv + silu. Emits u and new_conv_state.
// (R1/R7 exact)
__global__ __launch_bounds__(256) void combine1(
    const float* __restrict__ part, const float* __restrict__ b_in,
    const float* __restrict__ conv_state, const float* __restrict__ conv_weight,
    float* __restrict__ u_ws, float* __restrict__ ncs) {
  int idx = blockIdx.x * 256 + threadIdx.x;   // b*DI + d, < 524288
  int d = idx & (DI - 1);
  float xp = b_in[d];
#pragma unroll
  for (int s = 0; s < 4; ++s) xp += part[(size_t)s * (BB * DI) + idx];
  const float* cs = conv_state + (size_t)idx * 3;
  float4 w4 = *(const float4*)(conv_weight + d * 4);
  float c0 = cs[0], c1 = cs[1], c2 = cs[2];
  float sv = c0 * w4.x + c1 * w4.y + c2 * w4.z + xp * w4.w;
  float uu = sv / (1.f + __expf(-sv));
  u_ws[idx] = uu;
  float* o = ncs + (size_t)idx * 3;
  o[0] = c1; o[1] = c2; o[2] = xp;
}

// Streaming SSM (R1/R7 exact, unroll 4 — the empirically sharp optimum):
// new_ssm = exp(A)*ssm + B*u ; y_in = sum_n C*new_ssm + D*u
__global__ __launch_bounds__(256) void ssm_kernel(
    const float* __restrict__ ssm, const float* __restrict__ A,
    const float* __restrict__ Bp, const float* __restrict__ Cp,
    const float* __restrict__ Dp, const float* __restrict__ u,
    float* __restrict__ nss, float* __restrict__ y_in) {
  const int chunk = blockIdx.x >> 7;   // 0..3 (d-chunk of 1024)
  const int b = blockIdx.x & 127;
  const int d0 = chunk * 1024 + threadIdx.x * 4;
  f32x4 u4  = *(const f32x4*)(u + (size_t)b * DI + d0);
  f32x4 dp4 = *(const f32x4*)(Dp + d0);
  float accx = dp4[0]*u4[0], accy = dp4[1]*u4[1];
  float accz = dp4[2]*u4[2], accw = dp4[3]*u4[3];
  const float* sp = ssm + (size_t)b * NS * DI + d0;
  float* op = nss + (size_t)b * NS * DI + d0;
#pragma unroll 4
  for (int n = 0; n < NS; ++n) {
    f32x4 a4 = *(const f32x4*)(A + (size_t)n * DI + d0);            // L2-resident
    f32x4 s4 = __builtin_nontemporal_load((const f32x4*)(sp + (size_t)n * DI));
    float bn = Bp[n], cn = Cp[n];
    f32x4 ns4;
    ns4[0] = __expf(a4[0]) * s4[0] + bn * u4[0];
    ns4[1] = __expf(a4[1]) * s4[1] + bn * u4[1];
    ns4[2] = __expf(a4[2]) * s4[2] + bn * u4[2];
    ns4[3] = __expf(a4[3]) * s4[3] + bn * u4[3];
    __builtin_nontemporal_store(ns4, (f32x4*)(op + (size_t)n * DI));
    accx += cn * ns4[0]; accy += cn * ns4[1];
    accz += cn * ns4[2]; accw += cn * ns4[3];
  }
  f32x4 r; r[0] = accx; r[1] = accy; r[2] = accz; r[3] = accw;
  *(f32x4*)(y_in + (size_t)b * DI + d0) = r;
}

__global__ __launch_bounds__(256) void combine2(
    const float* __restrict__ part, const float* __restrict__ b_out,
    float* __restrict__ y_t) {
  int idx = blockIdx.x * 256 + threadIdx.x;  // b*DM + j, < 262144
  int j = idx & (DM - 1);
  float v = b_out[j];
#pragma unroll
  for (int s = 0; s < 8; ++s) v += part[(size_t)s * (BB * DM) + idx];
  y_t[idx] = v;
}

extern "C" void kernel_launch(void* const* d_in, const int* in_sizes, int n_in,
                              void* d_out, int out_size, void* d_ws, size_t ws_size,
                              hipStream_t stream) {
  const float* x_t         = (const float*)d_in[0];
  const float* conv_state  = (const float*)d_in[1];
  const float* ssm_state   = (const float*)d_in[2];
  const float* W_in        = (const float*)d_in[3];
  const float* b_in        = (const float*)d_in[4];
  const float* conv_weight = (const float*)d_in[5];
  const float* A           = (const float*)d_in[6];
  const float* Bp          = (const float*)d_in[7];
  const float* Cp          = (const float*)d_in[8];
  const float* Dp          = (const float*)d_in[9];
  const float* W_out       = (const float*)d_in[10];
  const float* b_out       = (const float*)d_in[11];

  float* y_t = (float*)d_out;                       // [128][2048]
  float* ncs = y_t + (size_t)BB * DM;               // [128][4096][3]
  float* nss = ncs + (size_t)BB * DI * 3;           // [128][128][4096]

  float* ws = (float*)d_ws;
  const size_t P1 = 4u * BB * DI;   // 2,097,152 floats
  const size_t P2 = 8u * BB * DM;   // 2,097,152 floats
  const size_t UV = (size_t)BB * DI;
  float *part1, *part2, *u_ws, *y_in;
  if (ws_size >= (P1 + P2 + 2 * UV) * sizeof(float)) {
    part1 = ws; part2 = part1 + P1; u_ws = part2 + P2; y_in = u_ws + UV;
  } else {
    // GEMM1 partials are fully consumed before ssm_kernel writes nss region
    part1 = nss;
    part2 = ws; u_ws = part2 + P2; y_in = u_ws + UV;
  }

  gemm_bf16<DI, DM, 4><<<dim3(512), dim3(256), 0, stream>>>(x_t, W_in, part1);
  combine1<<<dim3(2048), dim3(256), 0, stream>>>(part1, b_in, conv_state,
                                                 conv_weight, u_ws, ncs);
  ssm_kernel<<<dim3(512), dim3(256), 0, stream>>>(ssm_state, A, Bp, Cp, Dp,
                                                  u_ws, nss, y_in);
  gemm_bf16<DM, DI, 8><<<dim3(512), dim3(256), 0, stream>>>(y_in, W_out, part2);
  combine2<<<dim3(1024), dim3(256), 0, stream>>>(part2, b_out, y_t);
}